// Round 12
// baseline (35.586 us; speedup 1.0000x reference)
//
#include <hip/hip_runtime.h>
#include <hip/hip_bf16.h>

#define D 128
#define Nn 512
#define Bb 2

typedef __bf16 bf16x8_t __attribute__((ext_vector_type(8)));
typedef unsigned int u32x4_t __attribute__((ext_vector_type(4)));
typedef float f32x4_t __attribute__((ext_vector_type(4)));
typedef float f32x8_t __attribute__((ext_vector_type(8)));

// ---------------------------------------------------------------------------
// Kernel 1: A16[b,i,e] = bf16((dom*evo)@W1[:D] + b1); C16[b,i,e] = bf16((dom*evo)@W1[D:])
// 2 rows per block (512 blocks), W1 column stream shared 2-ways.
// Blocks 0..7 additionally emit W2T[e][k] = bf16(W2[k][e])  (64 x 128, 16 KB).
// ---------------------------------------------------------------------------
__global__ __launch_bounds__(256)
void precompute_ac(const float* __restrict__ dom, const float* __restrict__ evo,
                   const float* __restrict__ W1, const float* __restrict__ b1,
                   const float* __restrict__ W2,
                   __bf16* __restrict__ A16, __bf16* __restrict__ C16,
                   __bf16* __restrict__ W2T) {
    const int t = threadIdx.x;
    const int base = blockIdx.x * 2;
    if (blockIdx.x < 8) {
#pragma unroll
        for (int z = 0; z < 4; ++z) {
            int idx = z * 256 + t;                 // 0..1023
            int e = blockIdx.x * 8 + (idx >> 7);   // 8 e-rows per block
            int k = idx & 127;
            W2T[e * 128 + k] = (__bf16)W2[k * 64 + e];
        }
    }
    __shared__ float g2[2][D];
    {
        int r = t >> 7, c = t & 127;
        size_t off = (size_t)(base + r) * D + c;
        g2[r][c] = dom[off] * evo[off];
    }
    __syncthreads();
    const int half = t >> 7;                       // 0 -> A, 1 -> C
    const int e = t & 127;
    const float* Wp = W1 + half * D * D;
    float a0 = 0.f, a1 = 0.f;
#pragma unroll 16
    for (int dp = 0; dp < D; ++dp) {
        float w = Wp[dp * D + e];
        a0 = fmaf(g2[0][dp], w, a0);
        a1 = fmaf(g2[1][dp], w, a1);
    }
    if (half == 0) {
        float bb = b1[e];
        A16[(size_t)(base + 0) * D + e] = (__bf16)(a0 + bb);
        A16[(size_t)(base + 1) * D + e] = (__bf16)(a1 + bb);
    } else {
        C16[(size_t)(base + 0) * D + e] = (__bf16)a0;
        C16[(size_t)(base + 1) * D + e] = (__bf16)a1;
    }
}

// sum across each 16-lane row via DPP row_shr; FULL SUM LANDS IN ROW-LANE 15.
__device__ __forceinline__ float row16_reduce(float x) {
    int v = __builtin_bit_cast(int, x);
    x += __builtin_bit_cast(float, __builtin_amdgcn_update_dpp(0, v, 0x118, 0xf, 0xf, false));
    v = __builtin_bit_cast(int, x);
    x += __builtin_bit_cast(float, __builtin_amdgcn_update_dpp(0, v, 0x114, 0xf, 0xf, false));
    v = __builtin_bit_cast(int, x);
    x += __builtin_bit_cast(float, __builtin_amdgcn_update_dpp(0, v, 0x112, 0xf, 0xf, false));
    v = __builtin_bit_cast(int, x);
    x += __builtin_bit_cast(float, __builtin_amdgcn_update_dpp(0, v, 0x111, 0xf, 0xf, false));
    return x;
}

// expand 4 dwords of packed bf16 pairs into f32x8 (dword-wise: 2 VALU / 2 elems)
__device__ __forceinline__ f32x8_t expand_bf16x8(u32x4_t d) {
    f32x8_t r;
#pragma unroll
    for (int z = 0; z < 4; ++z) {
        r[2 * z]     = __builtin_bit_cast(float, d[z] << 16);
        r[2 * z + 1] = __builtin_bit_cast(float, d[z] & 0xffff0000u);
    }
    return r;
}

// ---------------------------------------------------------------------------
// Kernel 2: WAVE-AUTONOMOUS upper-triangle compute. One wave = one
// (b, i, j-chunk-64) unit; 4608 units = 1152 blocks x 4 independent waves.
// NO __syncthreads, NO LDS.  Per wave: A row (expand once), all 16 W2
// fragments in registers (loaded once from L2-resident W2T), then per active
// j-tile: h-build -> 16 MFMA -> DPP reduce -> sigmoid -> direct f32x4 store
// of the 16-value row segment (4 lanes x 16B = one 64B line).
// Diagonal-straddle tiles write 0 for j<=i (mirror overwrites j<i later).
// __launch_bounds__(256,3): cap 168 VGPR so wf/abv stay register-resident.
// ---------------------------------------------------------------------------
__global__ __launch_bounds__(256, 3)
void coevo_upper(const __bf16* __restrict__ A16, const __bf16* __restrict__ Cm,
                 const __bf16* __restrict__ W2T, const float* __restrict__ b2,
                 const float* __restrict__ W3, const float* __restrict__ b3,
                 float* __restrict__ out) {
    const int lane = threadIdx.x & 63;
    const int m = lane & 15;
    const int q = lane >> 4;

    int w = blockIdx.x * 4 + (threadIdx.x >> 6);   // 0..4607
    const int b = (w >= 2304) ? 1 : 0;
    w -= b * 2304;
    // chunk c starts at offset 32c(c+1); i in [0, 64(c+1))
    int chunk = 0;
#pragma unroll
    for (int cc = 1; cc < 8; ++cc) if (w >= 32 * cc * (cc + 1)) chunk = cc;
    const int i = w - 32 * chunk * (chunk + 1);

    // ---- A row (bf16, b1 folded) -> f32 via dword expand (once per wave)
    const u32x4_t* Ag = (const u32x4_t*)(A16 + ((size_t)(b * Nn + i)) * D);
    f32x8_t abv[4];
#pragma unroll
    for (int kk = 0; kk < 4; ++kk) abv[kk] = expand_bf16x8(Ag[kk * 4 + q]);

    // ---- all 16 W2 fragments into registers (L2-hot, once per wave)
    const bf16x8_t* W2g = (const bf16x8_t*)W2T;    // granule idx = e*16 + kk*4 + q
    bf16x8_t wf[4][4];
#pragma unroll
    for (int et = 0; et < 4; ++et)
#pragma unroll
        for (int kk = 0; kk < 4; ++kk)
            wf[et][kk] = W2g[(et * 16 + m) * 16 + kk * 4 + q];

    // ---- epilogue constants for this lane's columns e = et*16 + m
    float b2v[4], w3v[4];
#pragma unroll
    for (int et = 0; et < 4; ++et) {
        b2v[et] = b2[et * 16 + m];
        w3v[et] = W3[et * 16 + m];
    }
    const float b3s = b3[0];

    const u32x4_t* Cg = (const u32x4_t*)(Cm + ((size_t)b * Nn + (size_t)chunk * 64) * D);

#pragma unroll
    for (int jt = 0; jt < 4; ++jt) {
        if (chunk * 64 + jt * 16 + 15 < i) continue;   // tile fully below diag
        const int r0 = jt * 16 + m;                    // this lane's j row

        // ---- build H fragments: h = relu(a + c)
        bf16x8_t af[4];
#pragma unroll
        for (int kk = 0; kk < 4; ++kk) {
            f32x8_t c8 = expand_bf16x8(Cg[r0 * 16 + kk * 4 + q]);
            f32x8_t t8 = __builtin_elementwise_max(abv[kk] + c8, (f32x8_t)0.f);
            af[kk] = __builtin_convertvector(t8, bf16x8_t);
        }

        // ---- GEMM + epilogue fused per et (acc stays at 4 VGPR)
        float part[4] = {0.f, 0.f, 0.f, 0.f};
#pragma unroll
        for (int et = 0; et < 4; ++et) {
            f32x4_t a = {0.f, 0.f, 0.f, 0.f};
#pragma unroll
            for (int kk = 0; kk < 4; ++kk)
                a = __builtin_amdgcn_mfma_f32_16x16x32_bf16(af[kk], wf[et][kk], a, 0, 0, 0);
#pragma unroll
            for (int r = 0; r < 4; ++r)
                part[r] = fmaf(fmaxf(a[r] + b2v[et], 0.f), w3v[et], part[r]);
        }

        // ---- DPP reduce over 16 e-lanes (result in m==15), sigmoid, store
        float red[4];
#pragma unroll
        for (int r = 0; r < 4; ++r) red[r] = row16_reduce(part[r]);
        if (m == 15) {
            const int j0 = chunk * 64 + jt * 16 + q * 4;
            f32x4_t v;
#pragma unroll
            for (int r = 0; r < 4; ++r) {
                const int j = j0 + r;
                float sv = 1.f / (1.f + expf(-(red[r] + b3s)));
                v[r] = (j > i) ? sv : 0.f;         // j<=i: 0 (mirror fills j<i)
            }
            *(f32x4_t*)(out + ((size_t)b * Nn + i) * Nn + j0) = v;
        }
    }
}

// ---------------------------------------------------------------------------
// Kernel 3: fill strictly-lower triangle from the upper one, 64x64 LDS tiles.
// Coalesced full-line reads AND writes. 36 tiles/batch (R >= C).
// ---------------------------------------------------------------------------
__global__ __launch_bounds__(256)
void mirror_lower(float* __restrict__ out) {
    const int t = threadIdx.x;
    int u = blockIdx.x;
    const int b = (u >= 36) ? 1 : 0;
    u -= b * 36;
    int R = 0;
#pragma unroll
    for (int rr = 1; rr < 8; ++rr) if (u >= rr * (rr + 1) / 2) R = rr;
    const int Cc = u - R * (R + 1) / 2;            // Cc <= R

    __shared__ float ts[64 * 65];
    float* ob = out + (size_t)b * Nn * Nn;

#pragma unroll
    for (int it = 0; it < 4; ++it) {
        int f = it * 256 + t;                      // f32x4 unit 0..1023
        int sr = f >> 4, sc = (f & 15) * 4;
        f32x4_t v = *(const f32x4_t*)(ob + (size_t)(Cc * 64 + sr) * Nn + R * 64 + sc);
        ts[sr * 65 + sc + 0] = v[0];
        ts[sr * 65 + sc + 1] = v[1];
        ts[sr * 65 + sc + 2] = v[2];
        ts[sr * 65 + sc + 3] = v[3];
    }
    __syncthreads();
#pragma unroll
    for (int it = 0; it < 4; ++it) {
        int f = it * 256 + t;
        int dr = f >> 4, dc = (f & 15) * 4;
        float v0 = ts[(dc + 0) * 65 + dr];
        float v1 = ts[(dc + 1) * 65 + dr];
        float v2 = ts[(dc + 2) * 65 + dr];
        float v3 = ts[(dc + 3) * 65 + dr];
        size_t o = (size_t)(R * 64 + dr) * Nn + Cc * 64 + dc;
        if (R != Cc) {
            f32x4_t v; v[0] = v0; v[1] = v1; v[2] = v2; v[3] = v3;
            *(f32x4_t*)(ob + o) = v;
        } else {                                   // diagonal tile: dr > dc+z only
            if (dr > dc + 0) ob[o + 0] = v0;
            if (dr > dc + 1) ob[o + 1] = v1;
            if (dr > dc + 2) ob[o + 2] = v2;
            if (dr > dc + 3) ob[o + 3] = v3;
        }
    }
}

extern "C" void kernel_launch(void* const* d_in, const int* in_sizes, int n_in,
                              void* d_out, int out_size, void* d_ws, size_t ws_size,
                              hipStream_t stream) {
    const float* dom = (const float*)d_in[0];
    const float* evo = (const float*)d_in[1];
    const float* W1  = (const float*)d_in[2];
    const float* b1  = (const float*)d_in[3];
    const float* W2  = (const float*)d_in[4];
    const float* b2  = (const float*)d_in[5];
    const float* W3  = (const float*)d_in[6];
    const float* b3  = (const float*)d_in[7];
    float* out = (float*)d_out;

    __bf16* A16 = (__bf16*)d_ws;                         // [B][N][D] bf16 (256 KB)
    __bf16* C16 = A16 + (size_t)Bb * Nn * D;             // [B][N][D] bf16 (256 KB)
    __bf16* W2T = C16 + (size_t)Bb * Nn * D;             // [64][128] bf16 (16 KB)

    precompute_ac<<<Bb * Nn / 2, 256, 0, stream>>>(dom, evo, W1, b1, W2, A16, C16, W2T);
    coevo_upper<<<1152, 256, 0, stream>>>(A16, C16, W2T, b2, W3, b3, out);
    mirror_lower<<<Bb * 36, 256, 0, stream>>>(out);
}

// Round 13
// 33.216 us; speedup vs baseline: 1.0714x; 1.0714x over previous
//
#include <hip/hip_runtime.h>
#include <hip/hip_bf16.h>

#define D 128
#define Nn 512
#define Bb 2

typedef __bf16 bf16x8_t __attribute__((ext_vector_type(8)));
typedef unsigned int u32x4_t __attribute__((ext_vector_type(4)));
typedef float f32x4_t __attribute__((ext_vector_type(4)));
typedef float f32x8_t __attribute__((ext_vector_type(8)));

// ---------------------------------------------------------------------------
// Kernel 1: A16[b,i,e] = bf16((dom*evo)@W1[:D] + b1); C16[b,i,e] = bf16((dom*evo)@W1[D:])
// 2 rows per block (512 blocks), W1 column stream shared 2-ways.
// Blocks 0..7 additionally emit W2T[e][k] = bf16(W2[k][e])  (64 x 128, 16 KB).
// ---------------------------------------------------------------------------
__global__ __launch_bounds__(256)
void precompute_ac(const float* __restrict__ dom, const float* __restrict__ evo,
                   const float* __restrict__ W1, const float* __restrict__ b1,
                   const float* __restrict__ W2,
                   __bf16* __restrict__ A16, __bf16* __restrict__ C16,
                   __bf16* __restrict__ W2T) {
    const int t = threadIdx.x;
    const int base = blockIdx.x * 2;
    if (blockIdx.x < 8) {
#pragma unroll
        for (int z = 0; z < 4; ++z) {
            int idx = z * 256 + t;                 // 0..1023
            int e = blockIdx.x * 8 + (idx >> 7);   // 8 e-rows per block
            int k = idx & 127;
            W2T[e * 128 + k] = (__bf16)W2[k * 64 + e];
        }
    }
    __shared__ float g2[2][D];
    {
        int r = t >> 7, c = t & 127;
        size_t off = (size_t)(base + r) * D + c;
        g2[r][c] = dom[off] * evo[off];
    }
    __syncthreads();
    const int half = t >> 7;                       // 0 -> A, 1 -> C
    const int e = t & 127;
    const float* Wp = W1 + half * D * D;
    float a0 = 0.f, a1 = 0.f;
#pragma unroll 16
    for (int dp = 0; dp < D; ++dp) {
        float w = Wp[dp * D + e];
        a0 = fmaf(g2[0][dp], w, a0);
        a1 = fmaf(g2[1][dp], w, a1);
    }
    if (half == 0) {
        float bb = b1[e];
        A16[(size_t)(base + 0) * D + e] = (__bf16)(a0 + bb);
        A16[(size_t)(base + 1) * D + e] = (__bf16)(a1 + bb);
    } else {
        C16[(size_t)(base + 0) * D + e] = (__bf16)a0;
        C16[(size_t)(base + 1) * D + e] = (__bf16)a1;
    }
}

// sum across each 16-lane row via DPP row_shr; FULL SUM LANDS IN ROW-LANE 15.
__device__ __forceinline__ float row16_reduce(float x) {
    int v = __builtin_bit_cast(int, x);
    x += __builtin_bit_cast(float, __builtin_amdgcn_update_dpp(0, v, 0x118, 0xf, 0xf, false));
    v = __builtin_bit_cast(int, x);
    x += __builtin_bit_cast(float, __builtin_amdgcn_update_dpp(0, v, 0x114, 0xf, 0xf, false));
    v = __builtin_bit_cast(int, x);
    x += __builtin_bit_cast(float, __builtin_amdgcn_update_dpp(0, v, 0x112, 0xf, 0xf, false));
    v = __builtin_bit_cast(int, x);
    x += __builtin_bit_cast(float, __builtin_amdgcn_update_dpp(0, v, 0x111, 0xf, 0xf, false));
    return x;
}

// expand 4 dwords of packed bf16 pairs into f32x8 (dword-wise: 2 VALU / 2 elems)
__device__ __forceinline__ f32x8_t expand_bf16x8(u32x4_t d) {
    f32x8_t r;
#pragma unroll
    for (int z = 0; z < 4; ++z) {
        r[2 * z]     = __builtin_bit_cast(float, d[z] << 16);
        r[2 * z + 1] = __builtin_bit_cast(float, d[z] & 0xffff0000u);
    }
    return r;
}

// ---------------------------------------------------------------------------
// Kernel 2: round-8 structure (1152 blocks, 4 waves = 4 i's of one i-group,
// in-block LDS-tile mirror, 2 launches total) with FRONT-LOADED global loads:
// per wave, A row + jt{0,1} C tiles + ALL 16 W2 fragments issued back-to-back
// at wave start (LLC latency paid once, not per jt); C tiles 2+2 pipelined in
// NAMED register buffers.  W2 in registers; LDS = output tile only (1 KB).
// No min-waves clamp: allocator free to keep ~160-200 VGPRs live.
// ---------------------------------------------------------------------------
__global__ __launch_bounds__(256)
void coevo_main(const __bf16* __restrict__ A16, const __bf16* __restrict__ Cm,
                const __bf16* __restrict__ W2T, const float* __restrict__ b2,
                const float* __restrict__ W3, const float* __restrict__ b3,
                float* __restrict__ out) {
    const int tid  = threadIdx.x;
    const int wave = tid >> 6;
    const int lane = tid & 63;
    const int m = lane & 15;
    const int q = lane >> 4;

    int u = blockIdx.x;
    const int b = (u >= 576) ? 1 : 0;
    u -= b * 576;
    int chunk = 0;
#pragma unroll
    for (int cc = 1; cc < 8; ++cc) if (u >= 8 * cc * (cc + 1)) chunk = cc;
    const int g = u - 8 * chunk * (chunk + 1);     // 0 .. 16*(chunk+1)-1
    const int i = g * 4 + wave;
    const int i0 = g * 4;

    __shared__ float tile[4][64];                  // 1 KB: the ONLY LDS

    // ================= front-loaded global loads =================
    const u32x4_t* Ag = (const u32x4_t*)(A16 + ((size_t)(b * Nn + i)) * D);
    const u32x4_t* Cg = (const u32x4_t*)(Cm + ((size_t)b * Nn + (size_t)chunk * 64) * D);
    const bf16x8_t* W2g = (const bf16x8_t*)W2T;    // granule idx = e*16 + kk*4 + q

    u32x4_t ab16_0 = Ag[0 * 4 + q], ab16_1 = Ag[1 * 4 + q];
    u32x4_t ab16_2 = Ag[2 * 4 + q], ab16_3 = Ag[3 * 4 + q];

    u32x4_t crA[4], crB[4];                        // jt0 / jt1 C tiles
#pragma unroll
    for (int kk = 0; kk < 4; ++kk) crA[kk] = Cg[(0 * 16 + m) * 16 + kk * 4 + q];
#pragma unroll
    for (int kk = 0; kk < 4; ++kk) crB[kk] = Cg[(1 * 16 + m) * 16 + kk * 4 + q];

    bf16x8_t wf[4][4];                             // all 16 W2 fragments
#pragma unroll
    for (int et = 0; et < 4; ++et)
#pragma unroll
        for (int kk = 0; kk < 4; ++kk)
            wf[et][kk] = W2g[(et * 16 + m) * 16 + kk * 4 + q];

    float b2v[4], w3v[4];
#pragma unroll
    for (int et = 0; et < 4; ++et) {
        b2v[et] = b2[et * 16 + m];
        w3v[et] = W3[et * 16 + m];
    }
    const float b3s = b3[0];

    // expand A once (ab16_* die here)
    f32x8_t abv[4];
    abv[0] = expand_bf16x8(ab16_0);
    abv[1] = expand_bf16x8(ab16_1);
    abv[2] = expand_bf16x8(ab16_2);
    abv[3] = expand_bf16x8(ab16_3);

    // ================= per-tile compute =================
#define COMPUTE_TILE(JT, CR)                                                   \
    if (chunk * 64 + (JT) * 16 + 15 >= i) {                                    \
        bf16x8_t af[4];                                                        \
        _Pragma("unroll")                                                      \
        for (int kk = 0; kk < 4; ++kk) {                                       \
            f32x8_t c8 = expand_bf16x8(CR[kk]);                                \
            f32x8_t t8 = __builtin_elementwise_max(abv[kk] + c8, (f32x8_t)0.f);\
            af[kk] = __builtin_convertvector(t8, bf16x8_t);                    \
        }                                                                      \
        float part[4] = {0.f, 0.f, 0.f, 0.f};                                  \
        _Pragma("unroll")                                                      \
        for (int et = 0; et < 4; ++et) {                                       \
            f32x4_t a = {0.f, 0.f, 0.f, 0.f};                                  \
            _Pragma("unroll")                                                  \
            for (int kk = 0; kk < 4; ++kk)                                     \
                a = __builtin_amdgcn_mfma_f32_16x16x32_bf16(af[kk], wf[et][kk],\
                                                            a, 0, 0, 0);       \
            _Pragma("unroll")                                                  \
            for (int r = 0; r < 4; ++r)                                        \
                part[r] = fmaf(fmaxf(a[r] + b2v[et], 0.f), w3v[et], part[r]);  \
        }                                                                      \
        float red[4];                                                          \
        _Pragma("unroll")                                                      \
        for (int r = 0; r < 4; ++r) red[r] = row16_reduce(part[r]);            \
        if (m == 15) {                                                         \
            _Pragma("unroll")                                                  \
            for (int r = 0; r < 4; ++r) {                                      \
                int jc = (JT) * 16 + q * 4 + r;                                \
                tile[wave][jc] = 1.f / (1.f + expf(-(red[r] + b3s)));          \
            }                                                                  \
        }                                                                      \
    }

    COMPUTE_TILE(0, crA)
#pragma unroll
    for (int kk = 0; kk < 4; ++kk) crA[kk] = Cg[(2 * 16 + m) * 16 + kk * 4 + q];
    COMPUTE_TILE(1, crB)
#pragma unroll
    for (int kk = 0; kk < 4; ++kk) crB[kk] = Cg[(3 * 16 + m) * 16 + kk * 4 + q];
    COMPUTE_TILE(2, crA)
    COMPUTE_TILE(3, crB)
#undef COMPUTE_TILE

    __syncthreads();                               // tile complete

    // ---- upper store: row i, 64 cols (coalesced f32x4), diag = 0
    if ((tid & 63) < 16) {
        const int c4 = tid & 15;
        const int j0 = chunk * 64 + c4 * 4;
        float v0 = tile[wave][c4 * 4 + 0];
        float v1 = tile[wave][c4 * 4 + 1];
        float v2 = tile[wave][c4 * 4 + 2];
        float v3 = tile[wave][c4 * 4 + 3];
        float* op = out + ((size_t)b * Nn + i) * Nn + j0;
        if (j0 > i) {
            f32x4_t v; v[0] = v0; v[1] = v1; v[2] = v2; v[3] = v3;
            *(f32x4_t*)op = v;
        } else if (j0 + 3 >= i) {                  // straddles diagonal
            if (j0 + 0 > i) op[0] = v0; else if (j0 + 0 == i) op[0] = 0.f;
            if (j0 + 1 > i) op[1] = v1; else if (j0 + 1 == i) op[1] = 0.f;
            if (j0 + 2 > i) op[2] = v2; else if (j0 + 2 == i) op[2] = 0.f;
            if (j0 + 3 > i) op[3] = v3; else if (j0 + 3 == i) op[3] = 0.f;
        }                                          // else fully below diag: skip
    }
    // ---- lower (mirror) store: 64 rows j, cols i0..i0+3 (16B segments)
    if (tid < 64) {
        const int j = chunk * 64 + tid;
        float v0 = tile[0][tid], v1 = tile[1][tid], v2 = tile[2][tid], v3 = tile[3][tid];
        float* op = out + ((size_t)b * Nn + j) * Nn + i0;
        if (j > i0 + 3) {
            f32x4_t v; v[0] = v0; v[1] = v1; v[2] = v2; v[3] = v3;
            *(f32x4_t*)op = v;
        } else {
            if (j > i0 + 0) op[0] = v0;
            if (j > i0 + 1) op[1] = v1;
            if (j > i0 + 2) op[2] = v2;
            if (j > i0 + 3) op[3] = v3;
        }
    }
}

extern "C" void kernel_launch(void* const* d_in, const int* in_sizes, int n_in,
                              void* d_out, int out_size, void* d_ws, size_t ws_size,
                              hipStream_t stream) {
    const float* dom = (const float*)d_in[0];
    const float* evo = (const float*)d_in[1];
    const float* W1  = (const float*)d_in[2];
    const float* b1  = (const float*)d_in[3];
    const float* W2  = (const float*)d_in[4];
    const float* b2  = (const float*)d_in[5];
    const float* W3  = (const float*)d_in[6];
    const float* b3  = (const float*)d_in[7];
    float* out = (float*)d_out;

    __bf16* A16 = (__bf16*)d_ws;                         // [B][N][D] bf16 (256 KB)
    __bf16* C16 = A16 + (size_t)Bb * Nn * D;             // [B][N][D] bf16 (256 KB)
    __bf16* W2T = C16 + (size_t)Bb * Nn * D;             // [64][128] bf16 (16 KB)

    precompute_ac<<<Bb * Nn / 2, 256, 0, stream>>>(dom, evo, W1, b1, W2, A16, C16, W2T);
    coevo_main<<<Bb * 576, 256, 0, stream>>>(A16, C16, W2T, b2, W3, b3, out);
}

// Round 14
// 25.674 us; speedup vs baseline: 1.3861x; 1.2937x over previous
//
#include <hip/hip_runtime.h>
#include <hip/hip_bf16.h>

#define D 128
#define Nn 512
#define Bb 2

typedef __bf16 bf16x8_t __attribute__((ext_vector_type(8)));
typedef unsigned short u16x8_t __attribute__((ext_vector_type(8)));
typedef float f32x4_t __attribute__((ext_vector_type(4)));
typedef float f32x8_t __attribute__((ext_vector_type(8)));

// ---------------------------------------------------------------------------
// Kernel 1: A16[b,i,e] = bf16((dom*evo)@W1[:D] + b1); C16[b,i,e] = bf16((dom*evo)@W1[D:])
// 2 rows per block (512 blocks), W1 column stream shared 2-ways.
// Blocks 0..7 additionally emit W2T[e][k] = bf16(W2[k][e])  (64 x 128, 16 KB).
// ---------------------------------------------------------------------------
__global__ __launch_bounds__(256)
void precompute_ac(const float* __restrict__ dom, const float* __restrict__ evo,
                   const float* __restrict__ W1, const float* __restrict__ b1,
                   const float* __restrict__ W2,
                   __bf16* __restrict__ A16, __bf16* __restrict__ C16,
                   __bf16* __restrict__ W2T) {
    const int t = threadIdx.x;
    const int base = blockIdx.x * 2;
    if (blockIdx.x < 8) {
#pragma unroll
        for (int z = 0; z < 4; ++z) {
            int idx = z * 256 + t;                 // 0..1023
            int e = blockIdx.x * 8 + (idx >> 7);   // 8 e-rows per block
            int k = idx & 127;
            W2T[e * 128 + k] = (__bf16)W2[k * 64 + e];
        }
    }
    __shared__ float g2[2][D];
    {
        int r = t >> 7, c = t & 127;
        size_t off = (size_t)(base + r) * D + c;
        g2[r][c] = dom[off] * evo[off];
    }
    __syncthreads();
    const int half = t >> 7;                       // 0 -> A, 1 -> C
    const int e = t & 127;
    const float* Wp = W1 + half * D * D;
    float a0 = 0.f, a1 = 0.f;
#pragma unroll 16
    for (int dp = 0; dp < D; ++dp) {
        float w = Wp[dp * D + e];
        a0 = fmaf(g2[0][dp], w, a0);
        a1 = fmaf(g2[1][dp], w, a1);
    }
    if (half == 0) {
        float bb = b1[e];
        A16[(size_t)(base + 0) * D + e] = (__bf16)(a0 + bb);
        A16[(size_t)(base + 1) * D + e] = (__bf16)(a1 + bb);
    } else {
        C16[(size_t)(base + 0) * D + e] = (__bf16)a0;
        C16[(size_t)(base + 1) * D + e] = (__bf16)a1;
    }
}

// sum across each 16-lane row via DPP row_shr; FULL SUM LANDS IN ROW-LANE 15.
__device__ __forceinline__ float row16_reduce(float x) {
    int v = __builtin_bit_cast(int, x);
    x += __builtin_bit_cast(float, __builtin_amdgcn_update_dpp(0, v, 0x118, 0xf, 0xf, false));
    v = __builtin_bit_cast(int, x);
    x += __builtin_bit_cast(float, __builtin_amdgcn_update_dpp(0, v, 0x114, 0xf, 0xf, false));
    v = __builtin_bit_cast(int, x);
    x += __builtin_bit_cast(float, __builtin_amdgcn_update_dpp(0, v, 0x112, 0xf, 0xf, false));
    v = __builtin_bit_cast(int, x);
    x += __builtin_bit_cast(float, __builtin_amdgcn_update_dpp(0, v, 0x111, 0xf, 0xf, false));
    return x;
}

// ---------------------------------------------------------------------------
// Kernel 2 (champion, round 8): grid = the 1152 active (b, i-group-4,
// j-chunk-64) units.  4 waves, wave = one i.  NO C staging: c-fragments read
// straight from L2/LLC per jt (C is 256 KB bf16, read-shared chip-wide).
// LDS = W2T (16 KB, 16B-granule XOR swizzle key=row&15) + output tile (1 KB).
// __launch_bounds__(256,5).  DPP row-reduce (result in m==15), sigmoid;
// upper rows stored coalesced, lower mirror as 16B column segments. Diag = 0.
// ---------------------------------------------------------------------------
__global__ __launch_bounds__(256, 5)
void coevo_main(const __bf16* __restrict__ A16, const __bf16* __restrict__ Cm,
                const __bf16* __restrict__ W2T, const float* __restrict__ b2,
                const float* __restrict__ W3, const float* __restrict__ b3,
                float* __restrict__ out) {
    const int tid  = threadIdx.x;
    const int wave = tid >> 6;
    const int lane = tid & 63;
    const int m = lane & 15;
    const int q = lane >> 4;

    int u = blockIdx.x;
    const int b = (u >= 576) ? 1 : 0;
    u -= b * 576;
    int chunk = 0;
#pragma unroll
    for (int cc = 1; cc < 8; ++cc) if (u >= 8 * cc * (cc + 1)) chunk = cc;
    const int g = u - 8 * chunk * (chunk + 1);     // 0 .. 16*(chunk+1)-1
    const int i = g * 4 + wave;
    const int i0 = g * 4;

    __shared__ __bf16 w2s[64 * 128];               // 16 KB, swizzled
    __shared__ float  tile[4][64];                 // block output tile

    // ---- A row (bf16, b1 folded): 4 x 16B loads, issued first
    const u16x8_t* Ag8 = (const u16x8_t*)(A16 + ((size_t)(b * Nn + i)) * D);
    u16x8_t ab16[4];
#pragma unroll
    for (int kk = 0; kk < 4; ++kk) ab16[kk] = Ag8[kk * 4 + q];

    // ---- stage W2T into LDS: 1024 granules of 16B, 4 per thread, swizzled
    {
        f32x4_t* w2v = (f32x4_t*)w2s;
        const f32x4_t* W2Tg = (const f32x4_t*)W2T;
#pragma unroll
        for (int it = 0; it < 4; ++it) {
            int f = it * 256 + tid;
            int r = f >> 4, gi = f & 15;
            w2v[r * 16 + (gi ^ (r & 15))] = W2Tg[f];
        }
    }

    // ---- expand A to f32 once (32 VGPR)
    f32x8_t abv[4];
#pragma unroll
    for (int kk = 0; kk < 4; ++kk) {
#pragma unroll
        for (int z = 0; z < 8; ++z)
            abv[kk][z] = __builtin_bit_cast(float, (unsigned)ab16[kk][z] << 16);
    }

    // ---- epilogue constants for this lane's columns e = et*16 + m
    float b2v[4], w3v[4];
#pragma unroll
    for (int et = 0; et < 4; ++et) {
        b2v[et] = b2[et * 16 + m];
        w3v[et] = W3[et * 16 + m];
    }
    const float b3s = b3[0];

    __syncthreads();

    const u16x8_t*  Cg8 = (const u16x8_t*)(Cm + ((size_t)b * Nn + (size_t)chunk * 64) * D);
    const bf16x8_t* w2r = (const bf16x8_t*)w2s;

#pragma unroll
    for (int jt = 0; jt < 4; ++jt) {
        if (chunk * 64 + jt * 16 + 15 < i) continue;   // tile entirely below diag
        const int r0 = jt * 16 + m;                    // this lane's j row

        // ---- build H fragments: h = relu(a + c), c straight from L2/LLC
        bf16x8_t af[4];
#pragma unroll
        for (int kk = 0; kk < 4; ++kk) {
            u16x8_t cr = Cg8[r0 * 16 + kk * 4 + q];
            f32x8_t c8;
#pragma unroll
            for (int z = 0; z < 8; ++z)
                c8[z] = __builtin_bit_cast(float, (unsigned)cr[z] << 16);
            f32x8_t t8 = __builtin_elementwise_max(abv[kk] + c8, (f32x8_t)0.f);
            af[kk] = __builtin_convertvector(t8, bf16x8_t);
        }

        // ---- GEMM + epilogue fused per et (acc stays at 4 VGPR)
        float part[4] = {0.f, 0.f, 0.f, 0.f};
#pragma unroll
        for (int et = 0; et < 4; ++et) {
            bf16x8_t wf[4];
#pragma unroll
            for (int kk = 0; kk < 4; ++kk)
                wf[kk] = w2r[(et * 16 + m) * 16 + ((kk * 4 + q) ^ m)];
            f32x4_t a = {0.f, 0.f, 0.f, 0.f};
#pragma unroll
            for (int kk = 0; kk < 4; ++kk)
                a = __builtin_amdgcn_mfma_f32_16x16x32_bf16(af[kk], wf[kk], a, 0, 0, 0);
#pragma unroll
            for (int r = 0; r < 4; ++r)
                part[r] = fmaf(fmaxf(a[r] + b2v[et], 0.f), w3v[et], part[r]);
        }

        // ---- DPP reduce over 16 e-lanes (result in m==15), sigmoid, park
        float red[4];
#pragma unroll
        for (int r = 0; r < 4; ++r) red[r] = row16_reduce(part[r]);
        if (m == 15) {
#pragma unroll
            for (int r = 0; r < 4; ++r) {
                int jc = jt * 16 + q * 4 + r;
                tile[wave][jc] = 1.f / (1.f + expf(-(red[r] + b3s)));
            }
        }
    }

    __syncthreads();

    // ---- upper store: row i, 64 cols (coalesced f32x4), diag = 0
    if ((tid & 63) < 16) {
        const int c4 = tid & 15;
        const int j0 = chunk * 64 + c4 * 4;
        float v0 = tile[wave][c4 * 4 + 0];
        float v1 = tile[wave][c4 * 4 + 1];
        float v2 = tile[wave][c4 * 4 + 2];
        float v3 = tile[wave][c4 * 4 + 3];
        float* op = out + ((size_t)b * Nn + i) * Nn + j0;
        if (j0 > i) {
            f32x4_t v; v[0] = v0; v[1] = v1; v[2] = v2; v[3] = v3;
            *(f32x4_t*)op = v;
        } else if (j0 + 3 >= i) {                  // straddles diagonal
            if (j0 + 0 > i) op[0] = v0; else if (j0 + 0 == i) op[0] = 0.f;
            if (j0 + 1 > i) op[1] = v1; else if (j0 + 1 == i) op[1] = 0.f;
            if (j0 + 2 > i) op[2] = v2; else if (j0 + 2 == i) op[2] = 0.f;
            if (j0 + 3 > i) op[3] = v3; else if (j0 + 3 == i) op[3] = 0.f;
        }                                          // else fully below diag: skip
    }
    // ---- lower (mirror) store: 64 rows j, cols i0..i0+3 (16B segments)
    if (tid < 64) {
        const int j = chunk * 64 + tid;
        float v0 = tile[0][tid], v1 = tile[1][tid], v2 = tile[2][tid], v3 = tile[3][tid];
        float* op = out + ((size_t)b * Nn + j) * Nn + i0;
        if (j > i0 + 3) {
            f32x4_t v; v[0] = v0; v[1] = v1; v[2] = v2; v[3] = v3;
            *(f32x4_t*)op = v;
        } else {
            if (j > i0 + 0) op[0] = v0;
            if (j > i0 + 1) op[1] = v1;
            if (j > i0 + 2) op[2] = v2;
            if (j > i0 + 3) op[3] = v3;
        }
    }
}

extern "C" void kernel_launch(void* const* d_in, const int* in_sizes, int n_in,
                              void* d_out, int out_size, void* d_ws, size_t ws_size,
                              hipStream_t stream) {
    const float* dom = (const float*)d_in[0];
    const float* evo = (const float*)d_in[1];
    const float* W1  = (const float*)d_in[2];
    const float* b1  = (const float*)d_in[3];
    const float* W2  = (const float*)d_in[4];
    const float* b2  = (const float*)d_in[5];
    const float* W3  = (const float*)d_in[6];
    const float* b3  = (const float*)d_in[7];
    float* out = (float*)d_out;

    __bf16* A16 = (__bf16*)d_ws;                         // [B][N][D] bf16 (256 KB)
    __bf16* C16 = A16 + (size_t)Bb * Nn * D;             // [B][N][D] bf16 (256 KB)
    __bf16* W2T = C16 + (size_t)Bb * Nn * D;             // [64][128] bf16 (16 KB)

    precompute_ac<<<Bb * Nn / 2, 256, 0, stream>>>(dom, evo, W1, b1, W2, A16, C16, W2T);
    coevo_main<<<Bb * 576, 256, 0, stream>>>(A16, C16, W2T, b2, W3, b3, out);
}